// Round 12
// baseline (188.841 us; speedup 1.0000x reference)
//
#include <hip/hip_runtime.h>

#define NBINS   20
#define NSETS   32          // replicated count-accumulator sets (power of 2)
#define BLOCKS  2048
#define TPB     256

__device__ __forceinline__ int bin_of(float t)
{
    return min(max((int)(t * 20.0f), 0), NBINS - 1);   // same bin fn as all passing rounds
}

__device__ __forceinline__ void count_body(const float4 t, int (&cnt)[NBINS])
{
    int b0 = bin_of(t.x), b1 = bin_of(t.y), b2 = bin_of(t.z), b3 = bin_of(t.w);
    #pragma unroll
    for (int bb = 0; bb < NBINS; ++bb) {
        cnt[bb] += __popcll(__ballot(b0 == bb)) + __popcll(__ballot(b1 == bb))
                 + __popcll(__ballot(b2 == bb)) + __popcll(__ballot(b3 == bb));
    }
}

__device__ __forceinline__ float wsse_body(const float4 p, const float4 t,
                                           const float* __restrict__ wl, float acc)
{
    float w0 = wl[bin_of(t.x)], w1 = wl[bin_of(t.y)];
    float w2 = wl[bin_of(t.z)], w3 = wl[bin_of(t.w)];
    float d0 = p.x - t.x, d1 = p.y - t.y, d2 = p.z - t.z, d3 = p.w - t.w;
    acc = fmaf(d0 * d0, w0, acc);
    acc = fmaf(d1 * d1, w1, acc);
    acc = fmaf(d2 * d2, w2, acc);
    acc = fmaf(d3 * d3, w3, acc);
    return acc;
}

// ---------------- Pass A: exact bin counts via wave ballot ----------------
// r11: WIDTH-4 load batch (4 targ tiles = 4 KB in flight per wave) in ONE
// basic block. r8 proved the scheduler clusters unconditional same-BB loads
// when registers allow; rotation pipelines (r3/r5/r10) get collapsed instead.
// (TPB,2) -> 256-VGPR cap: no pressure to sink loads; #pragma unroll 1 keeps
// the batch at 4 tiles (not 8x more -> r8's spill).
__global__ __launch_bounds__(TPB, 2)
void dwmse_count(const float* __restrict__ targ, float* __restrict__ ws,
                 int n, int setMask)
{
    __shared__ int hc[(TPB / 64) * NBINS];
    const int tid  = threadIdx.x;
    const int lane = tid & 63;
    const int wv   = tid >> 6;

    int cnt[NBINS];
    #pragma unroll
    for (int b = 0; b < NBINS; ++b) cnt[b] = 0;

    const int n4 = n >> 2;
    const float4* t4 = reinterpret_cast<const float4*>(targ);
    const int idx0 = blockIdx.x * TPB + tid;
    const int W    = gridDim.x * TPB;

    const int iters4 = n4 / (4 * W);          // width-4 macro-iterations (2 @ N=2^24)
    int base = iters4 * 4 * W;
    const int leftT = n4 - base;
    const int ls    = leftT / W;              // 0..3 full single-tile strides
    const int remT  = leftT - ls * W;         // partial stride

    {
        const float4* tt = t4 + idx0;
        #pragma unroll 1
        for (int it = 0; it < iters4; ++it) {
            float4 t0 = tt[0];
            float4 t1 = tt[W];
            float4 t2 = tt[2 * W];
            float4 t3 = tt[3 * W];
            tt += 4 * W;
            count_body(t0, cnt);
            count_body(t1, cnt);
            count_body(t2, cnt);
            count_body(t3, cnt);
        }
    }
    #pragma unroll 1
    for (int k = 0; k < ls; ++k) {            // uniform trip count -> no divergence
        count_body(t4[base + k * W + idx0], cnt);
    }
    base += ls * W;
    // partial stride (threads idx0 < remT), predicated via b = -1
    {
        int b0 = -1, b1 = -1, b2 = -1, b3 = -1;
        if (idx0 < remT) {
            float4 t = t4[base + idx0];
            b0 = bin_of(t.x); b1 = bin_of(t.y); b2 = bin_of(t.z); b3 = bin_of(t.w);
        }
        #pragma unroll
        for (int bb = 0; bb < NBINS; ++bb) {
            cnt[bb] += __popcll(__ballot(b0 == bb)) + __popcll(__ballot(b1 == bb))
                     + __popcll(__ballot(b2 == bb)) + __popcll(__ballot(b3 == bb));
        }
    }
    // scalar tail (n % 4 elements), predicated single shot
    {
        int b0 = -1;
        const int k = (n4 << 2) + idx0;
        if (k < n) b0 = bin_of(targ[k]);
        #pragma unroll
        for (int bb = 0; bb < NBINS; ++bb)
            cnt[bb] += __popcll(__ballot(b0 == bb));
    }

    // lane bb exports cnt[bb] (wave-uniform -> 20 cndmask once per wave)
    int myc = 0;
    #pragma unroll
    for (int bb = 0; bb < NBINS; ++bb) myc = (lane == bb) ? cnt[bb] : myc;
    if (lane < NBINS) hc[wv * NBINS + lane] = myc;
    __syncthreads();
    if (tid < NBINS) {
        int s = 0;
        #pragma unroll
        for (int w = 0; w < TPB / 64; ++w) s += hc[w * NBINS + tid];
        const int set = (int)(blockIdx.x) & setMask;
        unsafeAtomicAdd(&ws[set * NBINS + tid], (float)s);  // counts <= 2^24: exact in f32
    }
}

// ---------------- Pass C: weighted SSE in one stream ----------------
// r11: WIDTH-4 batch -> 8 independent dwordx4 loads (8 KB) in flight per wave
// in one basic block. ~32 waves/CU x 8 KB = 256 KB/CU in flight vs ~10 KB
// Little's-law need at 6.3 TB/s -> latency can't bind unless the platform caps
// BW. Watch: VGPR ~56-72 and WRITE_SIZE ~64 (no spill) or the test is void.
__global__ __launch_bounds__(TPB, 2)
void dwmse_wsse(const float* __restrict__ pred, const float* __restrict__ targ,
                const float* __restrict__ ws, float* __restrict__ out,
                int n, int nsets, float inv_n)
{
    __shared__ float wl[NBINS];
    __shared__ float hr[TPB / 64];
    const int tid = threadIdx.x;

    // ---- per-block weight build (wave 0), identical math to the old pass2 ----
    if (tid < 64) {
        const int t = tid;
        float cntv = 0.0f;
        if (t < NBINS) {
            for (int s = 0; s < nsets; ++s) cntv += ws[s * NBINS + t];
        }
        float w = 0.0f;
        if (t < NBINS) {
            float c = fmaxf(cntv, 1.0f);
            w = __powf(c, -0.9f);
        }
        float s2 = w;
        #pragma unroll
        for (int off = 32; off > 0; off >>= 1) s2 += __shfl_down(s2, off);
        s2 = __shfl(s2, 0);
        float wb = (s2 > 0.0f) ? (w * (20.0f / s2)) : w;
        wb = fmaxf(wb, 1.0f);
        if (t < NBINS) wl[t] = wb;
    }
    __syncthreads();

    float acc = 0.0f;

    const int n4 = n >> 2;
    const float4* p4 = reinterpret_cast<const float4*>(pred);
    const float4* t4 = reinterpret_cast<const float4*>(targ);
    const int idx0 = blockIdx.x * TPB + tid;
    const int W    = gridDim.x * TPB;

    const int iters4 = n4 / (4 * W);
    int base = iters4 * 4 * W;
    const int leftT = n4 - base;
    const int ls    = leftT / W;
    const int remT  = leftT - ls * W;

    {
        const float4* pp = p4 + idx0;
        const float4* tt = t4 + idx0;
        #pragma unroll 1
        for (int it = 0; it < iters4; ++it) {
            float4 p0 = pp[0];
            float4 p1 = pp[W];
            float4 p2 = pp[2 * W];
            float4 p3 = pp[3 * W];
            float4 t0 = tt[0];
            float4 t1 = tt[W];
            float4 t2 = tt[2 * W];
            float4 t3 = tt[3 * W];
            pp += 4 * W; tt += 4 * W;
            acc = wsse_body(p0, t0, wl, acc);
            acc = wsse_body(p1, t1, wl, acc);
            acc = wsse_body(p2, t2, wl, acc);
            acc = wsse_body(p3, t3, wl, acc);
        }
    }
    #pragma unroll 1
    for (int k = 0; k < ls; ++k) {
        acc = wsse_body(p4[base + k * W + idx0], t4[base + k * W + idx0], wl, acc);
    }
    base += ls * W;
    if (idx0 < remT) {
        acc = wsse_body(p4[base + idx0], t4[base + idx0], wl, acc);
    }
    for (int k = (n4 << 2) + idx0; k < n; k += W) {
        float t = targ[k];
        float d = pred[k] - t;
        acc = fmaf(d * d, wl[bin_of(t)], acc);
    }

    // ---- block reduction -> one atomic into (zeroed) out ----
    #pragma unroll
    for (int off = 32; off > 0; off >>= 1) acc += __shfl_down(acc, off);
    if ((tid & 63) == 0) hr[tid >> 6] = acc;
    __syncthreads();
    if (tid == 0) {
        float blk = 0.0f;
        #pragma unroll
        for (int w = 0; w < TPB / 64; ++w) blk += hr[w];
        unsafeAtomicAdd(out, blk * inv_n);
    }
}

extern "C" void kernel_launch(void* const* d_in, const int* in_sizes, int n_in,
                              void* d_out, int out_size, void* d_ws, size_t ws_size,
                              hipStream_t stream)
{
    const float* pred = (const float*)d_in[0];
    const float* targ = (const float*)d_in[1];
    float*       out  = (float*)d_out;
    float*       ws   = (float*)d_ws;
    const int n = in_sizes[0];

    int nsets = NSETS;
    while ((size_t)nsets * NBINS * sizeof(float) > ws_size && nsets > 1) nsets >>= 1;

    hipMemsetAsync(d_ws, 0, (size_t)nsets * NBINS * sizeof(float), stream);
    hipMemsetAsync(d_out, 0, sizeof(float), stream);   // out accumulates atomically
    dwmse_count<<<BLOCKS, TPB, 0, stream>>>(targ, ws, n, nsets - 1);
    dwmse_wsse<<<BLOCKS, TPB, 0, stream>>>(pred, targ, ws, out, n, nsets,
                                           1.0f / (float)n);
}

// Round 14
// 157.380 us; speedup vs baseline: 1.1999x; 1.1999x over previous
//
#include <hip/hip_runtime.h>

#define NBINS   20
#define NSETS   32          // replicated global accumulator slots (power of 2)
#define BLOCKS  2048
#define TPB     256
#define PACK    256.0f      // A = 256*cnt + sse ; per-thread cnt<=32, sse<32 -> exact decode

// Non-temporal (streaming) loads: same data, nt-flagged -> bypass L2/L3
// retention. Probe: is the ~3 TB/s delivered ceiling the L3 partial-hit path?
// __builtin_nontemporal_load needs a NATIVE clang vector type, not
// HIP_vector_type -> go through ext_vector_type(4) and bit-cast.
typedef float f32x4 __attribute__((ext_vector_type(4)));

__device__ __forceinline__ float4 ldnt4(const float4* p)
{
    f32x4 v = __builtin_nontemporal_load(reinterpret_cast<const f32x4*>(p));
    return make_float4(v.x, v.y, v.z, v.w);
}
__device__ __forceinline__ float ldnt1(const float* p)
{
    return __builtin_nontemporal_load(p);
}

// Per-tile compute: 4 elements -> packed (cnt,sse) routed into 20 register bins.
// All acc indexing is compile-time (full unroll) -> stays in VGPRs (no scratch).
__device__ __forceinline__ void body(const float4 p, const float4 t, float (&acc)[NBINS])
{
    float d0 = p.x - t.x; float a0 = fmaf(d0, d0, PACK);
    float d1 = p.y - t.y; float a1 = fmaf(d1, d1, PACK);
    float d2 = p.z - t.z; float a2 = fmaf(d2, d2, PACK);
    float d3 = p.w - t.w; float a3 = fmaf(d3, d3, PACK);
    int b0 = min(max((int)(t.x * 20.0f), 0), NBINS - 1);
    int b1 = min(max((int)(t.y * 20.0f), 0), NBINS - 1);
    int b2 = min(max((int)(t.z * 20.0f), 0), NBINS - 1);
    int b3 = min(max((int)(t.w * 20.0f), 0), NBINS - 1);
    #pragma unroll
    for (int bb = 0; bb < NBINS; ++bb) {
        float add = ((bb == b0) ? a0 : 0.0f) + ((bb == b1) ? a1 : 0.0f)
                  + ((bb == b2) ? a2 : 0.0f) + ((bb == b3) ? a3 : 0.0f);
        acc[bb] += add;
    }
}

// ---------------- Pass 1: per-bin packed (count,sse) histogram ----------------
// Base = r5 best-known (158.3 us bench, pass1 ~52 us, absmax 0). One variable
// changed: nt loads on the two input streams.
__global__ __launch_bounds__(TPB, 8)
void dwmse_pass1(const float* __restrict__ pred, const float* __restrict__ targ,
                 float* __restrict__ ws, int n, int setMask)
{
    __shared__ float h[NBINS * TPB];     // 20 KB -> 8 blocks/CU
    const int tid = threadIdx.x;

    float acc[NBINS];
    #pragma unroll
    for (int b = 0; b < NBINS; ++b) acc[b] = 0.0f;

    const int n4 = n >> 2;
    const float4* p4 = reinterpret_cast<const float4*>(pred);
    const float4* t4 = reinterpret_cast<const float4*>(targ);
    const int idx0    = blockIdx.x * TPB + tid;
    const int gstride = gridDim.x * TPB;

    const int iters = n4 / gstride;          // full tiles for every thread (8 @ N=2^24)
    const int rem   = n4 - iters * gstride;  // threads idx0 < rem do one extra tile

    if (iters >= 2) {
        const float4* pp = p4 + idx0;
        const float4* tt = t4 + idx0;
        float4 pa = ldnt4(pp);           float4 ta = ldnt4(tt);
        float4 pb = ldnt4(pp + gstride); float4 tb = ldnt4(tt + gstride);
        for (int it = 0; it < iters - 2; ++it) {
            float4 pc = ldnt4(pp + 2 * gstride);
            float4 tc = ldnt4(tt + 2 * gstride);
            pp += gstride; tt += gstride;
            body(pa, ta, acc);
            pa = pb; ta = tb;
            pb = pc; tb = tc;
        }
        body(pa, ta, acc);
        body(pb, tb, acc);
    } else if (iters == 1) {
        body(ldnt4(p4 + idx0), ldnt4(t4 + idx0), acc);
    }
    if (idx0 < rem) {
        body(ldnt4(p4 + iters * gstride + idx0), ldnt4(t4 + iters * gstride + idx0), acc);
    }
    // scalar tail (empty for N = 2^24)
    for (int k = (n4 << 2) + idx0; k < n; k += gstride) {
        float t = ldnt1(targ + k);
        float d = ldnt1(pred + k) - t; float a = fmaf(d, d, PACK);
        int b = min(max((int)(t * 20.0f), 0), NBINS - 1);
        #pragma unroll
        for (int bb = 0; bb < NBINS; ++bb) acc[bb] += (bb == b) ? a : 0.0f;
    }

    // ---- decode per thread (exact: cnt<=32, sse<32), stage sse in LDS ----
    #pragma unroll
    for (int b = 0; b < NBINS; ++b) {
        float A = acc[b];
        float c = floorf(A * (1.0f / 256.0f));
        float s = A - 256.0f * c;
        h[b * TPB + tid] = s;            // phase A payload
        acc[b] = c;                      // keep counts for phase B
    }
    __syncthreads();

    // ---- phase A: 160 readers, each sums 32 consecutive (staggered) slots ----
    const int rbin = tid >> 3;           // bin for readers (tid < 160)
    const int rchk = tid & 7;            // chunk within bin
    float pA = 0.0f;
    if (tid < NBINS * 8) {
        const int base = rbin * TPB + rchk * 32;
        #pragma unroll
        for (int k = 0; k < 32; ++k)
            pA += h[base + ((k + tid) & 31)];   // stagger -> conflict-free
    }
    pA += __shfl_down(pA, 4);            // combine 8 chunks (aligned groups)
    pA += __shfl_down(pA, 2);
    pA += __shfl_down(pA, 1);
    const float blk_sse = pA;            // valid at rchk==0

    __syncthreads();                     // phase A reads done -> reuse h
    #pragma unroll
    for (int b = 0; b < NBINS; ++b) h[b * TPB + tid] = acc[b];
    __syncthreads();

    float pB = 0.0f;
    if (tid < NBINS * 8) {
        const int base = rbin * TPB + rchk * 32;
        #pragma unroll
        for (int k = 0; k < 32; ++k)
            pB += h[base + ((k + tid) & 31)];
    }
    pB += __shfl_down(pB, 4);
    pB += __shfl_down(pB, 2);
    pB += __shfl_down(pB, 1);

    if (tid < NBINS * 8 && rchk == 0) {
        const int set = (int)(blockIdx.x) & setMask;
        unsafeAtomicAdd(&ws[set * 2 * NBINS + rbin], blk_sse);
        unsafeAtomicAdd(&ws[set * 2 * NBINS + NBINS + rbin], pB);
    }
}

// ---------------- Pass 2: weights + final scalar ----------------
__global__ void dwmse_pass2(const float* __restrict__ ws, float* __restrict__ out,
                            int nsets, float inv_n)
{
    const int t = threadIdx.x;   // 64 threads = 1 wave
    float col = 0.0f;
    if (t < 2 * NBINS) {
        for (int s = 0; s < nsets; ++s) col += ws[s * 2 * NBINS + t];
    }
    // lanes 0..19 hold sse_b; counts live in lanes 20..39
    float sse = col;
    float cnt = __shfl(col, t + 20);

    float w = 0.0f;
    if (t < NBINS) {
        float c = fmaxf(cnt, 1.0f);
        w = __powf(c, -0.9f);
    }
    float s = w;
    #pragma unroll
    for (int off = 32; off > 0; off >>= 1) s += __shfl_down(s, off);
    s = __shfl(s, 0);

    float wb = (s > 0.0f) ? (w * (20.0f / s)) : w;
    wb = fmaxf(wb, 1.0f);

    float contrib = (t < NBINS) ? (wb * sse) : 0.0f;
    #pragma unroll
    for (int off = 32; off > 0; off >>= 1) contrib += __shfl_down(contrib, off);

    if (t == 0) out[0] = contrib * inv_n;
}

extern "C" void kernel_launch(void* const* d_in, const int* in_sizes, int n_in,
                              void* d_out, int out_size, void* d_ws, size_t ws_size,
                              hipStream_t stream)
{
    const float* pred = (const float*)d_in[0];
    const float* targ = (const float*)d_in[1];
    float*       out  = (float*)d_out;
    float*       ws   = (float*)d_ws;
    const int n = in_sizes[0];

    int nsets = NSETS;
    while ((size_t)nsets * 2 * NBINS * sizeof(float) > ws_size && nsets > 1) nsets >>= 1;

    hipMemsetAsync(d_ws, 0, (size_t)nsets * 2 * NBINS * sizeof(float), stream);
    dwmse_pass1<<<BLOCKS, TPB, 0, stream>>>(pred, targ, ws, n, nsets - 1);
    dwmse_pass2<<<1, 64, 0, stream>>>(ws, out, nsets, 1.0f / (float)n);
}